// Round 1
// 552.839 us; speedup vs baseline: 1.8808x; 1.8808x over previous
//
#include <hip/hip_runtime.h>
#include <hip/hip_bf16.h>

#define N_NODES 10000
#define NHID 128
#define NEDGE 320000

typedef float  float4_t  __attribute__((ext_vector_type(4)));
typedef float  float2_t  __attribute__((ext_vector_type(2)));
typedef short  short8    __attribute__((ext_vector_type(8)));

// ---------- detect edge_index dtype: flag=1 if int64 (odd words all zero) ----------
__global__ void k_detect(const int* __restrict__ ei32, int* __restrict__ flag) {
    __shared__ int s_or;
    if (threadIdx.x == 0) s_or = 0;
    __syncthreads();
    int v = ei32[2 * threadIdx.x + 1] | ei32[2 * ((int)threadIdx.x + 256) + 1];
    if (v) atomicOr(&s_or, 1);
    __syncthreads();
    if (threadIdx.x == 0) flag[0] = (s_or == 0) ? 1 : 0;
}

__device__ inline int edge_at(const int* __restrict__ ei, int mode, int idx) {
    // mode=1: buffer is int64 little-endian, values < 2^31 -> low word at 2*idx
    return mode ? ei[2 * idx] : ei[idx];
}

// ---------- CSR build: count incoming edges per dst (int atomics) ----------
__global__ void k_count(const int* __restrict__ ei, const int* __restrict__ flag,
                        int* __restrict__ cnt) {
    int e = blockIdx.x * 256 + threadIdx.x;
    if (e >= NEDGE) return;
    int mode = flag[0];
    int dst = edge_at(ei, mode, NEDGE + e);
    atomicAdd(&cnt[dst], 1);
}

// ---------- exclusive prefix scan of cnt -> off[0..N], and cursor copy ----------
#define SCAN_T 1024
#define SCAN_CH 10   // ceil(10000/1024)
__global__ __launch_bounds__(SCAN_T)
void k_scan(const int* __restrict__ cnt, int* __restrict__ off, int* __restrict__ cur) {
    __shared__ int sums[SCAN_T];
    int t = threadIdx.x;
    int base = t * SCAN_CH;
    int loc[SCAN_CH];
    int s = 0;
#pragma unroll
    for (int i = 0; i < SCAN_CH; i++) {
        int idx = base + i;
        int v = (idx < N_NODES) ? cnt[idx] : 0;
        loc[i] = s;
        s += v;
    }
    sums[t] = s;
    __syncthreads();
    // Hillis-Steele inclusive scan over thread totals
    for (int d = 1; d < SCAN_T; d <<= 1) {
        int v = (t >= d) ? sums[t - d] : 0;
        __syncthreads();
        sums[t] += v;
        __syncthreads();
    }
    int pre = (t == 0) ? 0 : sums[t - 1];
#pragma unroll
    for (int i = 0; i < SCAN_CH; i++) {
        int idx = base + i;
        if (idx < N_NODES) {
            int o = pre + loc[i];
            off[idx] = o;
            cur[idx] = o;
        }
    }
    if (t == SCAN_T - 1) off[N_NODES] = sums[t];
}

// ---------- dinv = rsqrt(deg_in + 1 self loop), degree from CSR offsets ----------
__global__ void k_dinv(const int* __restrict__ off, float* __restrict__ dinv) {
    int i = blockIdx.x * 256 + threadIdx.x;
    if (i < N_NODES) dinv[i] = rsqrtf((float)(off[i + 1] - off[i]) + 1.0f);
}

// ---------- fill CSR: place src into its dst segment (one int atomic/edge) ----------
__global__ void k_fill(const int* __restrict__ ei, const int* __restrict__ flag,
                       int* __restrict__ cur, int* __restrict__ srcIdx) {
    int e = blockIdx.x * 256 + threadIdx.x;
    if (e >= NEDGE) return;
    int mode = flag[0];
    int src = edge_at(ei, mode, e);
    int dst = edge_at(ei, mode, NEDGE + e);
    int pos = atomicAdd(&cur[dst], 1);
    srcIdx[pos] = src;
}

// ---------- xw = x @ W  (8 rows/block, thread = 4 cols via float4) ----------
__global__ void k_xw(const float* __restrict__ x, const float* __restrict__ W,
                     float* __restrict__ xw) {
    __shared__ float xs[8 * 128];
    int t = threadIdx.x;
    int rowBase = blockIdx.x * 8;
    {   // stage 8 rows of x (1024 floats) with float4
        int idx = t * 4;
        int r = idx >> 7;
        int rr = rowBase + r;
        float4_t v = {0.f, 0.f, 0.f, 0.f};
        if (rr < N_NODES) v = *(const float4_t*)&x[rr * 128 + (idx & 127)];
        *(float4_t*)&xs[idx] = v;
    }
    __syncthreads();
    int c = t & 31;          // col group (4 cols)
    int rloc = t >> 5;       // 0..7
    int row = rowBase + rloc;
    float4_t acc = {0.f, 0.f, 0.f, 0.f};
#pragma unroll 8
    for (int k = 0; k < 128; k++) {
        float xv = xs[rloc * 128 + k];
        float4_t wv = *(const float4_t*)&W[k * 128 + c * 4];
        acc += xv * wv;
    }
    if (row < N_NODES) *(float4_t*)&xw[row * 128 + c * 4] = acc;
}

// ---------- gather + epilogue: one wave per node, lane = 2 features ----------
// h[dst] = relu( dinv[dst] * ( sum_src dinv[src]*xw[src] + dinv[dst]*xw[dst] ) + b )
__global__ __launch_bounds__(256)
void k_gather_h(const int* __restrict__ srcIdx, const int* __restrict__ off,
                const float* __restrict__ xw, const float* __restrict__ dinv,
                const float* __restrict__ b, __hip_bfloat16* __restrict__ hbf) {
    int t = threadIdx.x;
    int lane = t & 63;
    int node = blockIdx.x * 4 + (t >> 6);
    if (node >= N_NODES) return;
    int f = lane * 2;
    float di = dinv[node];
    float2_t acc = di * *(const float2_t*)&xw[node * 128 + f];   // self loop
    int e = off[node], end = off[node + 1];
    // 2-way unrolled edge loop: independent loads pipeline across iterations
    for (; e + 2 <= end; e += 2) {
        int s0 = srcIdx[e], s1 = srcIdx[e + 1];
        float w0 = dinv[s0], w1 = dinv[s1];
        float2_t v0 = *(const float2_t*)&xw[s0 * 128 + f];
        float2_t v1 = *(const float2_t*)&xw[s1 * 128 + f];
        acc += w0 * v0;
        acc += w1 * v1;
    }
    if (e < end) {
        int s0 = srcIdx[e];
        acc += dinv[s0] * *(const float2_t*)&xw[s0 * 128 + f];
    }
    float2_t bb = *(const float2_t*)&b[f];
    float2_t v = di * acc + bb;
    __hip_bfloat16* dst = &hbf[node * 128 + f];
    dst[0] = __float2bfloat16(fmaxf(v.x, 0.0f));
    dst[1] = __float2bfloat16(fmaxf(v.y, 0.0f));
}

// ---------- out = h @ h^T  (128x128 tile per block, K=128 single pass) ----------
#define LDSLD 136   // 128 + 8 pad: stride = 68 dwords == 4 mod 32 -> 2-way (free)
__global__ __launch_bounds__(256, 2)
void k_gemm(const __hip_bfloat16* __restrict__ h, float* __restrict__ out) {
    __shared__ unsigned short As[128][LDSLD];
    __shared__ unsigned short Bs[128][LDSLD];
    int by = blockIdx.y, bx = blockIdx.x;
    int t = threadIdx.x;
    const unsigned short* hu = (const unsigned short*)h;

    // full tile = 128 rows x 16 col-groups of 8 shorts = 2048 slots; 256 thr x 8 it
#pragma unroll
    for (int it = 0; it < 8; it++) {
        int c = t + it * 256;        // 0..2047
        int row = c >> 4;            // 0..127
        int col8 = (c & 15) * 8;     // 0,8,...,120
        int gra = by * 128 + row;
        float4_t va = {0.f, 0.f, 0.f, 0.f};
        if (gra < N_NODES) va = *(const float4_t*)&hu[gra * 128 + col8];
        *(float4_t*)&As[row][col8] = va;
        int grb = bx * 128 + row;
        float4_t vb = {0.f, 0.f, 0.f, 0.f};
        if (grb < N_NODES) vb = *(const float4_t*)&hu[grb * 128 + col8];
        *(float4_t*)&Bs[row][col8] = vb;
    }
    __syncthreads();

    int lane = t & 63, w = t >> 6;
    int wm = (w >> 1) * 64, wn = (w & 1) * 64;
    int quad = lane >> 4, l16 = lane & 15;

    float4_t acc[4][4] = {};
    short8 a_frag[4], b_frag[4];

#pragma unroll
    for (int ks = 0; ks < 4; ks++) {
        int k0 = ks * 32 + quad * 8;
#pragma unroll
        for (int mi = 0; mi < 4; mi++)
            a_frag[mi] = *(const short8*)&As[wm + mi * 16 + l16][k0];
#pragma unroll
        for (int ni = 0; ni < 4; ni++)
            b_frag[ni] = *(const short8*)&Bs[wn + ni * 16 + l16][k0];
#pragma unroll
        for (int mi = 0; mi < 4; mi++)
#pragma unroll
            for (int ni = 0; ni < 4; ni++)
                acc[mi][ni] = __builtin_amdgcn_mfma_f32_16x16x32_bf16(
                    a_frag[mi], b_frag[ni], acc[mi][ni], 0, 0, 0);
    }

#pragma unroll
    for (int mi = 0; mi < 4; mi++) {
        int gr0 = by * 128 + wm + mi * 16 + quad * 4;
#pragma unroll
        for (int r = 0; r < 4; r++) {
            int grow = gr0 + r;
            if (grow >= N_NODES) continue;
            long rowoff = (long)grow * N_NODES;
#pragma unroll
            for (int ni = 0; ni < 4; ni++) {
                int gcol = bx * 128 + wn + ni * 16 + l16;
                if (gcol < N_NODES)
                    __builtin_nontemporal_store(acc[mi][ni][r], &out[rowoff + gcol]);
            }
        }
    }
}

extern "C" void kernel_launch(void* const* d_in, const int* in_sizes, int n_in,
                              void* d_out, int out_size, void* d_ws, size_t ws_size,
                              hipStream_t stream) {
    const float* x  = (const float*)d_in[0];
    const int*   ei = (const int*)d_in[1];
    const float* W  = (const float*)d_in[2];
    const float* b  = (const float*)d_in[3];
    float* out = (float*)d_out;

    char* ws = (char*)d_ws;
    // workspace layout (all offsets 256B aligned)
    float* xw   = (float*)(ws);                    // 5,120,000 B
    float* dinv = (float*)(ws + 5120000);          //    40,000 B
    int*   flg  = (int*)  (ws + 5160192);          //         4 B
    int*   cnt  = (int*)  (ws + 5160448);          //    40,000 B
    int*   off  = (int*)  (ws + 5200640);          //    40,004 B (N+1)
    int*   cur  = (int*)  (ws + 5240832);          //    40,000 B
    int*   srcI = (int*)  (ws + 5281024);          // 1,280,000 B
    __hip_bfloat16* hbf = (__hip_bfloat16*)(ws + 6561024);  // 2,560,000 B

    hipMemsetAsync(cnt, 0, (size_t)N_NODES * sizeof(int), stream);
    k_detect<<<1, 256, 0, stream>>>(ei, flg);
    k_count<<<(NEDGE + 255) / 256, 256, 0, stream>>>(ei, flg, cnt);
    k_scan<<<1, SCAN_T, 0, stream>>>(cnt, off, cur);
    k_dinv<<<(N_NODES + 255) / 256, 256, 0, stream>>>(off, dinv);
    k_xw<<<(N_NODES + 7) / 8, 256, 0, stream>>>(x, W, xw);
    k_fill<<<(NEDGE + 255) / 256, 256, 0, stream>>>(ei, flg, cur, srcI);
    k_gather_h<<<(N_NODES + 3) / 4, 256, 0, stream>>>(srcI, off, xw, dinv, b, hbf);
    dim3 g((N_NODES + 127) / 128, (N_NODES + 127) / 128);
    k_gemm<<<g, 256, 0, stream>>>(hbf, out);
}

// Round 3
// 534.273 us; speedup vs baseline: 1.9461x; 1.0348x over previous
//
#include <hip/hip_runtime.h>
#include <hip/hip_bf16.h>

#define N_NODES 10000
#define NHID 128
#define NEDGE 320000

typedef float  float4_t   __attribute__((ext_vector_type(4)));
typedef float  float2_t   __attribute__((ext_vector_type(2)));
typedef float  float16_t  __attribute__((ext_vector_type(16)));
typedef short  short8     __attribute__((ext_vector_type(8)));

// ---------- detect edge_index dtype: flag=1 if int64 (odd words all zero) ----------
__global__ void k_detect(const int* __restrict__ ei32, int* __restrict__ flag) {
    __shared__ int s_or;
    if (threadIdx.x == 0) s_or = 0;
    __syncthreads();
    int v = ei32[2 * threadIdx.x + 1] | ei32[2 * ((int)threadIdx.x + 256) + 1];
    if (v) atomicOr(&s_or, 1);
    __syncthreads();
    if (threadIdx.x == 0) flag[0] = (s_or == 0) ? 1 : 0;
}

__device__ inline int edge_at(const int* __restrict__ ei, int mode, int idx) {
    // mode=1: buffer is int64 little-endian, values < 2^31 -> low word at 2*idx
    return mode ? ei[2 * idx] : ei[idx];
}

// ---------- CSR build: count incoming edges per dst (int atomics) ----------
__global__ void k_count(const int* __restrict__ ei, const int* __restrict__ flag,
                        int* __restrict__ cnt) {
    int e = blockIdx.x * 256 + threadIdx.x;
    if (e >= NEDGE) return;
    int mode = flag[0];
    int dst = edge_at(ei, mode, NEDGE + e);
    atomicAdd(&cnt[dst], 1);
}

// ---------- exclusive prefix scan of cnt -> off[0..N], cursor copy, dinv fused ----------
#define SCAN_T 1024
#define SCAN_CH 10   // ceil(10000/1024)
__global__ __launch_bounds__(SCAN_T)
void k_scan(const int* __restrict__ cnt, int* __restrict__ off, int* __restrict__ cur,
            float* __restrict__ dinv) {
    __shared__ int sums[SCAN_T];
    int t = threadIdx.x;
    int base = t * SCAN_CH;
    int loc[SCAN_CH];
    int s = 0;
#pragma unroll
    for (int i = 0; i < SCAN_CH; i++) {
        int idx = base + i;
        int v = (idx < N_NODES) ? cnt[idx] : 0;
        loc[i] = s;
        s += v;
    }
    sums[t] = s;
    __syncthreads();
    // Hillis-Steele inclusive scan over thread totals
    for (int d = 1; d < SCAN_T; d <<= 1) {
        int v = (t >= d) ? sums[t - d] : 0;
        __syncthreads();
        sums[t] += v;
        __syncthreads();
    }
    int pre = (t == 0) ? 0 : sums[t - 1];
#pragma unroll
    for (int i = 0; i < SCAN_CH; i++) {
        int idx = base + i;
        if (idx < N_NODES) {
            int o = pre + loc[i];
            off[idx] = o;
            cur[idx] = o;
            // degree = cnt[idx] (+1 self loop); reload is an L2 hit
            dinv[idx] = rsqrtf((float)cnt[idx] + 1.0f);
        }
    }
    if (t == SCAN_T - 1) off[N_NODES] = sums[t];
}

// ---------- fill CSR: place src into its dst segment (one int atomic/edge) ----------
__global__ void k_fill(const int* __restrict__ ei, const int* __restrict__ flag,
                       int* __restrict__ cur, int* __restrict__ srcIdx) {
    int e = blockIdx.x * 256 + threadIdx.x;
    if (e >= NEDGE) return;
    int mode = flag[0];
    int src = edge_at(ei, mode, e);
    int dst = edge_at(ei, mode, NEDGE + e);
    int pos = atomicAdd(&cur[dst], 1);
    srcIdx[pos] = src;
}

// ---------- xw = x @ W  (8 rows/block, thread = 4 cols via float4) ----------
__global__ void k_xw(const float* __restrict__ x, const float* __restrict__ W,
                     float* __restrict__ xw) {
    __shared__ float xs[8 * 128];
    int t = threadIdx.x;
    int rowBase = blockIdx.x * 8;
    {   // stage 8 rows of x (1024 floats) with float4
        int idx = t * 4;
        int r = idx >> 7;
        int rr = rowBase + r;
        float4_t v = {0.f, 0.f, 0.f, 0.f};
        if (rr < N_NODES) v = *(const float4_t*)&x[rr * 128 + (idx & 127)];
        *(float4_t*)&xs[idx] = v;
    }
    __syncthreads();
    int c = t & 31;          // col group (4 cols)
    int rloc = t >> 5;       // 0..7
    int row = rowBase + rloc;
    float4_t acc = {0.f, 0.f, 0.f, 0.f};
#pragma unroll 8
    for (int k = 0; k < 128; k++) {
        float xv = xs[rloc * 128 + k];
        float4_t wv = *(const float4_t*)&W[k * 128 + c * 4];
        acc += xv * wv;
    }
    if (row < N_NODES) *(float4_t*)&xw[row * 128 + c * 4] = acc;
}

// ---------- gather + epilogue: one wave per node, lane = 2 features ----------
// h[dst] = relu( dinv[dst] * ( sum_src dinv[src]*xw[src] + dinv[dst]*xw[dst] ) + b )
__global__ __launch_bounds__(256)
void k_gather_h(const int* __restrict__ srcIdx, const int* __restrict__ off,
                const float* __restrict__ xw, const float* __restrict__ dinv,
                const float* __restrict__ b, __hip_bfloat16* __restrict__ hbf) {
    int t = threadIdx.x;
    int lane = t & 63;
    int node = blockIdx.x * 4 + (t >> 6);
    if (node >= N_NODES) return;
    int f = lane * 2;
    float di = dinv[node];
    float2_t acc = di * *(const float2_t*)&xw[node * 128 + f];   // self loop
    int e = off[node], end = off[node + 1];
    // 2-way unrolled edge loop: independent loads pipeline across iterations
    for (; e + 2 <= end; e += 2) {
        int s0 = srcIdx[e], s1 = srcIdx[e + 1];
        float w0 = dinv[s0], w1 = dinv[s1];
        float2_t v0 = *(const float2_t*)&xw[s0 * 128 + f];
        float2_t v1 = *(const float2_t*)&xw[s1 * 128 + f];
        acc += w0 * v0;
        acc += w1 * v1;
    }
    if (e < end) {
        int s0 = srcIdx[e];
        acc += dinv[s0] * *(const float2_t*)&xw[s0 * 128 + f];
    }
    float2_t bb = *(const float2_t*)&b[f];
    float2_t v = di * acc + bb;
    __hip_bfloat16* dst = &hbf[node * 128 + f];
    dst[0] = __float2bfloat16(fmaxf(v.x, 0.0f));
    dst[1] = __float2bfloat16(fmaxf(v.y, 0.0f));
}

// ---------- out = h @ h^T  (128x128 tile, 32x32x16 MFMA, XOR-swizzled LDS) ----------
// LDS[row][slot] holds global chunk (slot ^ (row&15)); chunks are 8 bf16 (16 B).
// Read-side bank math: addr = row*256 + slot*16; bank depends only on slot;
// each 16B slot is claimed by exactly 4 of 64 lanes -> 8 dword-claims/bank = optimal.
__global__ __launch_bounds__(256, 2)
void k_gemm(const __hip_bfloat16* __restrict__ h, float* __restrict__ out) {
    __shared__ unsigned short As[128][128];
    __shared__ unsigned short Bs[128][128];
    int by = blockIdx.y, bx = blockIdx.x;
    int t = threadIdx.x;
    const unsigned short* hu = (const unsigned short*)h;

#pragma unroll
    for (int it = 0; it < 8; it++) {
        int c = t + it * 256;        // 0..2047
        int row = c >> 4;            // 0..127
        int ch  = c & 15;            // global chunk (8 shorts)
        int sl  = ch ^ (row & 15);   // swizzled LDS slot
        int gra = by * 128 + row;
        float4_t va = {0.f, 0.f, 0.f, 0.f};
        if (gra < N_NODES) va = *(const float4_t*)&hu[gra * 128 + ch * 8];
        *(float4_t*)&As[row][sl * 8] = va;
        int grb = bx * 128 + row;
        float4_t vb = {0.f, 0.f, 0.f, 0.f};
        if (grb < N_NODES) vb = *(const float4_t*)&hu[grb * 128 + ch * 8];
        *(float4_t*)&Bs[row][sl * 8] = vb;
    }
    __syncthreads();

    int lane = t & 63, w = t >> 6;
    int wm = (w >> 1) * 64, wn = (w & 1) * 64;   // wave's 64x64 sub-tile
    int l32 = lane & 31;
    int hi  = lane >> 5;                          // k-half selector

    float16_t acc[2][2] = {};
    short8 af[2], bf[2];

#pragma unroll
    for (int ks = 0; ks < 8; ks++) {
        int ch = ks * 2 + hi;                     // global k-chunk for this lane
#pragma unroll
        for (int mi = 0; mi < 2; mi++) {
            int r = wm + mi * 32 + l32;
            af[mi] = *(const short8*)&As[r][(ch ^ (r & 15)) * 8];
        }
#pragma unroll
        for (int ni = 0; ni < 2; ni++) {
            int r = wn + ni * 32 + l32;
            bf[ni] = *(const short8*)&Bs[r][(ch ^ (r & 15)) * 8];
        }
#pragma unroll
        for (int mi = 0; mi < 2; mi++)
#pragma unroll
            for (int ni = 0; ni < 2; ni++)
                acc[mi][ni] = __builtin_amdgcn_mfma_f32_32x32x16_bf16(
                    af[mi], bf[ni], acc[mi][ni], 0, 0, 0);
    }

    // C/D layout (32x32): col = lane&31, row = (reg&3) + 8*(reg>>2) + 4*(lane>>5)
    // -> each store instruction writes two 128 B row segments (fully coalesced)
#pragma unroll
    for (int mi = 0; mi < 2; mi++)
#pragma unroll
        for (int ni = 0; ni < 2; ni++) {
            int gc = bx * 128 + wn + ni * 32 + l32;
            if (gc >= N_NODES) continue;
#pragma unroll
            for (int reg = 0; reg < 16; reg++) {
                int gr = by * 128 + wm + mi * 32 + (reg & 3) + 8 * (reg >> 2) + 4 * hi;
                if (gr < N_NODES)
                    __builtin_nontemporal_store(acc[mi][ni][reg],
                                                &out[(long)gr * N_NODES + gc]);
            }
        }
}

extern "C" void kernel_launch(void* const* d_in, const int* in_sizes, int n_in,
                              void* d_out, int out_size, void* d_ws, size_t ws_size,
                              hipStream_t stream) {
    const float* x  = (const float*)d_in[0];
    const int*   ei = (const int*)d_in[1];
    const float* W  = (const float*)d_in[2];
    const float* b  = (const float*)d_in[3];
    float* out = (float*)d_out;

    char* ws = (char*)d_ws;
    // workspace layout (all offsets 256B aligned)
    float* xw   = (float*)(ws);                    // 5,120,000 B
    float* dinv = (float*)(ws + 5120000);          //    40,000 B
    int*   flg  = (int*)  (ws + 5160192);          //         4 B
    int*   cnt  = (int*)  (ws + 5160448);          //    40,000 B
    int*   off  = (int*)  (ws + 5200640);          //    40,004 B (N+1)
    int*   cur  = (int*)  (ws + 5240832);          //    40,000 B
    int*   srcI = (int*)  (ws + 5281024);          // 1,280,000 B
    __hip_bfloat16* hbf = (__hip_bfloat16*)(ws + 6561024);  // 2,560,000 B

    hipMemsetAsync(cnt, 0, (size_t)N_NODES * sizeof(int), stream);
    k_detect<<<1, 256, 0, stream>>>(ei, flg);
    k_count<<<(NEDGE + 255) / 256, 256, 0, stream>>>(ei, flg, cnt);
    k_scan<<<1, SCAN_T, 0, stream>>>(cnt, off, cur, dinv);
    k_xw<<<(N_NODES + 7) / 8, 256, 0, stream>>>(x, W, xw);
    k_fill<<<(NEDGE + 255) / 256, 256, 0, stream>>>(ei, flg, cur, srcI);
    k_gather_h<<<(N_NODES + 3) / 4, 256, 0, stream>>>(srcI, off, xw, dinv, b, hbf);
    dim3 g((N_NODES + 127) / 128, (N_NODES + 127) / 128);
    k_gemm<<<g, 256, 0, stream>>>(hbf, out);
}